// Round 1
// baseline (87.212 us; speedup 1.0000x reference)
//
#include <hip/hip_runtime.h>
#include <math.h>

// RBF covariance: out[n][m] = softplus(variance_raw) * exp(-0.5 * ||x[n]/s - xx[m]/s||^2)
// with s = softplus(scale_raw), D = 8 fixed.
//
// Tile: each 256-thread block computes 16 (n) x 1024 (m) outputs.
// Thread t owns m-columns [m0 + 4t, m0 + 4t + 3]: 32 scaled xx floats in regs,
// loops over 16 pre-scaled x rows in LDS (pure broadcast reads), float4 stores.

#define TILE_N 16
#define BLOCK 256
#define D 8
#define M_PER_BLOCK (BLOCK * 4)   // 1024

__device__ __forceinline__ float softplus_f(float z) {
    // numerically stable: max(z,0) + log1p(exp(-|z|))
    return fmaxf(z, 0.0f) + log1pf(__expf(-fabsf(z)));
}

__global__ __launch_bounds__(BLOCK) void rbf_kernel(
    const float* __restrict__ x,          // (N, 8)
    const float* __restrict__ xx,         // (M, 8)
    const float* __restrict__ scale_raw,  // (8,)
    const float* __restrict__ var_raw,    // (1,)
    float* __restrict__ out,              // (N, M)
    int N, int M)
{
    __shared__ float s_xs[TILE_N][D];     // pre-scaled x rows for this block
    __shared__ float s_rscale[D];
    __shared__ float s_var;

    const int tid = threadIdx.x;
    const int m0 = blockIdx.x * M_PER_BLOCK + tid * 4;
    const int n0 = blockIdx.y * TILE_N;

    // Phase 1: hyperparameters (once per block)
    if (tid < D) {
        s_rscale[tid] = 1.0f / softplus_f(scale_raw[tid]);
    }
    if (tid == D) {
        s_var = softplus_f(var_raw[0]);
    }
    __syncthreads();

    // Phase 2: stage 16 scaled x rows (128 floats) into LDS
    if (tid < TILE_N * D) {
        const int r = tid / D, c = tid % D;
        s_xs[r][c] = x[(n0 + r) * D + c] * s_rscale[c];
    }
    __syncthreads();

    // Per-thread: load 4 xx rows, scale into registers
    float rs[D];
#pragma unroll
    for (int d = 0; d < D; ++d) rs[d] = s_rscale[d];

    float b[4][D];
    const float* xxp = xx + (size_t)m0 * D;
#pragma unroll
    for (int j = 0; j < 4; ++j) {
        const float4 lo = *(const float4*)(xxp + j * D);
        const float4 hi = *(const float4*)(xxp + j * D + 4);
        b[j][0] = lo.x * rs[0]; b[j][1] = lo.y * rs[1];
        b[j][2] = lo.z * rs[2]; b[j][3] = lo.w * rs[3];
        b[j][4] = hi.x * rs[4]; b[j][5] = hi.y * rs[5];
        b[j][6] = hi.z * rs[6]; b[j][7] = hi.w * rs[7];
    }

    const float var = s_var;

#pragma unroll
    for (int n = 0; n < TILE_N; ++n) {
        float a[D];
#pragma unroll
        for (int d = 0; d < D; ++d) a[d] = s_xs[n][d];  // broadcast, conflict-free

        float4 r;
        float* rp = &r.x;
#pragma unroll
        for (int j = 0; j < 4; ++j) {
            float d2 = 0.0f;
#pragma unroll
            for (int d = 0; d < D; ++d) {
                const float t = a[d] - b[j][d];
                d2 = fmaf(t, t, d2);
            }
            rp[j] = var * __expf(-0.5f * d2);
        }
        *(float4*)(out + (size_t)(n0 + n) * M + m0) = r;
    }
}

extern "C" void kernel_launch(void* const* d_in, const int* in_sizes, int n_in,
                              void* d_out, int out_size, void* d_ws, size_t ws_size,
                              hipStream_t stream) {
    const float* x    = (const float*)d_in[0];
    const float* xx   = (const float*)d_in[1];
    const float* sraw = (const float*)d_in[2];
    const float* vraw = (const float*)d_in[3];
    float* out = (float*)d_out;

    const int N = in_sizes[0] / D;   // 4096
    const int M = in_sizes[1] / D;   // 4096

    dim3 grid(M / M_PER_BLOCK, N / TILE_N);  // (4, 256)
    rbf_kernel<<<grid, BLOCK, 0, stream>>>(x, xx, sraw, vraw, out, N, M);
}

// Round 3
// 86.199 us; speedup vs baseline: 1.0118x; 1.0118x over previous
//
#include <hip/hip_runtime.h>
#include <math.h>

// RBF covariance: out[n][m] = var * exp(-0.5 * ||x[n]/s - xx[m]/s||^2),
// s = softplus(scale_raw), var = softplus(variance_raw), D = 8.
//
// Formulation (log2 domain, constants folded):
//   a' = (x/s) * sqrt(log2e),  b' = (xx/s) * sqrt(log2e)
//   arg2 = a'.b' - 0.5||a'||^2 - 0.5||b'||^2   ( = log2e * (-0.5 d2) )
//   out  = exp2( min(arg2 + log2(var), log2(var)) )   (clamp == maximum(d2,0))
// Inner loop per output: 8 fma (shared as v_pk_fma_f32 over m-pairs) + min + exp2.
//
// Tile: 256-thread block -> 16 (n) x 1024 (m); thread owns 4 m-columns.

#define TILE_N 16
#define BLOCK 256
#define D 8
#define M_PER_BLOCK (BLOCK * 4)   // 1024

typedef float v2f __attribute__((ext_vector_type(2)));
typedef float v4f __attribute__((ext_vector_type(4)));

__device__ __forceinline__ float softplus_f(float z) {
    return fmaxf(z, 0.0f) + log1pf(__expf(-fabsf(z)));
}

__device__ __forceinline__ float fast_exp2(float z) {
    return __builtin_exp2f(z);
}

__global__ __launch_bounds__(BLOCK) void rbf_kernel(
    const float* __restrict__ x,          // (N, 8)
    const float* __restrict__ xx,         // (M, 8)
    const float* __restrict__ scale_raw,  // (8,)
    const float* __restrict__ var_raw,    // (1,)
    float* __restrict__ out,              // (N, M)
    int N, int M)
{
    __shared__ float s_a[TILE_N][D];   // pre-scaled x rows (by sqrt(log2e)/scale)
    __shared__ float s_c[TILE_N];      // log2(var) - 0.5*||a'||^2
    __shared__ float s_rs[D];
    __shared__ float s_l2v;

    const int tid = threadIdx.x;
    const int m0 = blockIdx.x * M_PER_BLOCK + tid * 4;
    const int n0 = blockIdx.y * TILE_N;

    // hyperparameters once per block
    if (tid < D) {
        // 1.2011224... = sqrt(log2(e))
        s_rs[tid] = 1.2011224087864498f / softplus_f(scale_raw[tid]);
    }
    if (tid == D) {
        s_l2v = log2f(softplus_f(var_raw[0]));
    }
    __syncthreads();

    // stage 16 scaled x rows
    if (tid < TILE_N * D) {
        const int r = tid >> 3, c = tid & 7;
        s_a[r][c] = x[(n0 + r) * D + c] * s_rs[c];
    }

    // per-thread: 4 scaled xx rows into packed registers (pairs over m)
    float rs[D];
#pragma unroll
    for (int d = 0; d < D; ++d) rs[d] = s_rs[d];

    v2f b01[D], b23[D];
    {
        const float* xxp = xx + (size_t)m0 * D;
        float bj[4][D];
#pragma unroll
        for (int j = 0; j < 4; ++j) {
            const float4 lo = *(const float4*)(xxp + j * D);
            const float4 hi = *(const float4*)(xxp + j * D + 4);
            bj[j][0] = lo.x * rs[0]; bj[j][1] = lo.y * rs[1];
            bj[j][2] = lo.z * rs[2]; bj[j][3] = lo.w * rs[3];
            bj[j][4] = hi.x * rs[4]; bj[j][5] = hi.y * rs[5];
            bj[j][6] = hi.z * rs[6]; bj[j][7] = hi.w * rs[7];
        }
#pragma unroll
        for (int d = 0; d < D; ++d) {
            b01[d] = (v2f){bj[0][d], bj[1][d]};
            b23[d] = (v2f){bj[2][d], bj[3][d]};
        }
    }
    // 0.5*||b'||^2 per owned column, packed
    v2f h01 = {0.f, 0.f}, h23 = {0.f, 0.f};
#pragma unroll
    for (int d = 0; d < D; ++d) {
        h01 = __builtin_elementwise_fma(b01[d], b01[d], h01);
        h23 = __builtin_elementwise_fma(b23[d], b23[d], h23);
    }
    h01 *= 0.5f; h23 *= 0.5f;

    __syncthreads();

    // per-row constant c_n = log2(var) - 0.5*||a'||^2
    if (tid < TILE_N) {
        float s = 0.f;
#pragma unroll
        for (int d = 0; d < D; ++d) s = fmaf(s_a[tid][d], s_a[tid][d], s);
        s_c[tid] = s_l2v - 0.5f * s;
    }
    __syncthreads();

    const float l2v = s_l2v;

#pragma unroll
    for (int n = 0; n < TILE_N; ++n) {
        const float4 alo = *(const float4*)&s_a[n][0];   // ds_read_b128
        const float4 ahi = *(const float4*)&s_a[n][4];
        const float c = s_c[n];
        const float a_[D] = {alo.x, alo.y, alo.z, alo.w, ahi.x, ahi.y, ahi.z, ahi.w};

        v2f acc01 = (v2f){c, c} - h01;
        v2f acc23 = (v2f){c, c} - h23;
#pragma unroll
        for (int d = 0; d < D; ++d) {
            const v2f av = (v2f){a_[d], a_[d]};
            acc01 = __builtin_elementwise_fma(av, b01[d], acc01);  // v_pk_fma_f32
            acc23 = __builtin_elementwise_fma(av, b23[d], acc23);
        }

        v4f r;
        r.x = fast_exp2(fminf(acc01.x, l2v));
        r.y = fast_exp2(fminf(acc01.y, l2v));
        r.z = fast_exp2(fminf(acc23.x, l2v));
        r.w = fast_exp2(fminf(acc23.y, l2v));
        __builtin_nontemporal_store(r, (v4f*)(out + (size_t)(n0 + n) * M + m0));
    }
}

extern "C" void kernel_launch(void* const* d_in, const int* in_sizes, int n_in,
                              void* d_out, int out_size, void* d_ws, size_t ws_size,
                              hipStream_t stream) {
    const float* x    = (const float*)d_in[0];
    const float* xx   = (const float*)d_in[1];
    const float* sraw = (const float*)d_in[2];
    const float* vraw = (const float*)d_in[3];
    float* out = (float*)d_out;

    const int N = in_sizes[0] / D;   // 4096
    const int M = in_sizes[1] / D;   // 4096

    dim3 grid(M / M_PER_BLOCK, N / TILE_N);  // (4, 256)
    rbf_kernel<<<grid, BLOCK, 0, stream>>>(x, xx, sraw, vraw, out, N, M);
}